// Round 11
// baseline (1442.188 us; speedup 1.0000x reference)
//
#include <hip/hip_runtime.h>
#include <hip/hip_bf16.h>
#include <cstdint>
#include <cstddef>

#define T_TOK 16384
#define DIM   1024
#define HID   4096
#define NE    8
#define NSLOT 34816   /* 32768 + 8*256 max padded slots (256-aligned segments) */
#define BK 64

typedef __bf16 bf16_t;
typedef __bf16 bf16x8 __attribute__((ext_vector_type(8)));
typedef __bf16 bf16x4v __attribute__((ext_vector_type(4)));
typedef float  f32x4  __attribute__((ext_vector_type(4)));

__device__ __forceinline__ void gload_lds16(const void* g, const void* l) {
  __builtin_amdgcn_global_load_lds(
      (const __attribute__((address_space(1))) uint32_t*)(uintptr_t)g,
      (__attribute__((address_space(3))) uint32_t*)(uint32_t)(uintptr_t)l,
      16, 0, 0);
}

// meta layout (ints): [0..7]=counts, [8..15]=cursor, [16..24]=seg_base(9)

// setup: ptok=-1, meta=0, out=bias
__global__ __launch_bounds__(256) void setup_kernel(int* __restrict__ ptok,
                                                    int* __restrict__ meta,
                                                    float* __restrict__ out,
                                                    const float* __restrict__ bias) {
  int gi = blockIdx.x * 256 + threadIdx.x;
  if (gi < NSLOT) ptok[gi] = -1;
  if (gi < 16) meta[gi] = 0;
  const int n4 = T_TOK * DIM / 4;
  for (int i = gi; i < n4; i += gridDim.x * 256) {
    ((float4*)out)[i] = ((const float4*)bias)[i & 255];
  }
}

// router + fused f32->bf16 conversion of x into Xb (vectorized 32B/lane)
__global__ __launch_bounds__(256) void router_kernel(
    const float* __restrict__ x, const float* __restrict__ rw,
    float* __restrict__ logits, int* __restrict__ meta,
    int* __restrict__ te, float* __restrict__ tw, bf16_t* __restrict__ Xb) {
  const int lane = threadIdx.x & 63;
  const int t = blockIdx.x * 4 + (threadIdx.x >> 6);
  const float* xr = x + (size_t)t * DIM;
  float acc[NE] = {0.f,0.f,0.f,0.f,0.f,0.f,0.f,0.f};
#pragma unroll
  for (int j = 0; j < 2; ++j) {
    int d0 = j * 512 + lane * 8;
    float4 a = *(const float4*)(xr + d0);
    float4 b = *(const float4*)(xr + d0 + 4);
    bf16x8 o = { (bf16_t)a.x, (bf16_t)a.y, (bf16_t)a.z, (bf16_t)a.w,
                 (bf16_t)b.x, (bf16_t)b.y, (bf16_t)b.z, (bf16_t)b.w };
    *(bf16x8*)(Xb + (size_t)t * DIM + d0) = o;
    float xs[8] = {a.x, a.y, a.z, a.w, b.x, b.y, b.z, b.w};
#pragma unroll
    for (int k = 0; k < 8; ++k) {
      float4 wa = *(const float4*)(rw + (size_t)(d0 + k) * NE);
      float4 wb = *(const float4*)(rw + (size_t)(d0 + k) * NE + 4);
      acc[0] += xs[k] * wa.x; acc[1] += xs[k] * wa.y;
      acc[2] += xs[k] * wa.z; acc[3] += xs[k] * wa.w;
      acc[4] += xs[k] * wb.x; acc[5] += xs[k] * wb.y;
      acc[6] += xs[k] * wb.z; acc[7] += xs[k] * wb.w;
    }
  }
#pragma unroll
  for (int off = 32; off; off >>= 1) {
#pragma unroll
    for (int e = 0; e < NE; ++e) acc[e] += __shfl_down(acc[e], off);
  }
  if (lane == 0) {
    float m = acc[0];
#pragma unroll
    for (int e = 1; e < NE; ++e) m = fmaxf(m, acc[e]);
    float p[NE]; float s = 0.f;
#pragma unroll
    for (int e = 0; e < NE; ++e) { p[e] = expf(acc[e] - m); s += p[e]; }
    float inv = 1.0f / s;
    int e0 = 0;
#pragma unroll
    for (int e = 1; e < NE; ++e) if (p[e] > p[e0]) e0 = e;
    int e1 = (e0 == 0) ? 1 : 0;
#pragma unroll
    for (int e = 0; e < NE; ++e) if (e != e0 && p[e] > p[e1]) e1 = e;
#pragma unroll
    for (int e = 0; e < NE; ++e) logits[(size_t)t * NE + e] = acc[e];
    te[2 * t]     = e0;  te[2 * t + 1] = e1;
    tw[2 * t]     = p[e0] * inv;
    tw[2 * t + 1] = p[e1] * inv;
    atomicAdd(&meta[e0], 1);
    atomicAdd(&meta[e1], 1);
  }
}

// scatter (scan fused): every thread derives seg locally; block0 publishes
__global__ __launch_bounds__(256) void scatter_kernel(
    const int* __restrict__ te, const float* __restrict__ tw,
    int* __restrict__ meta, int* __restrict__ ptok, float* __restrict__ pw) {
  int counts[NE], seg[NE]; int s = 0;
#pragma unroll
  for (int e = 0; e < NE; ++e) counts[e] = meta[e];
#pragma unroll
  for (int e = 0; e < NE; ++e) { seg[e] = s; s += ((counts[e] + 255) / 256) * 256; }
  if (blockIdx.x == 0 && threadIdx.x == 0) {
    int* sg = meta + 16; int a = 0;
    for (int e = 0; e < NE; ++e) { sg[e] = a; a += ((counts[e] + 255) / 256) * 256; }
    sg[NE] = a;
  }
  int t = blockIdx.x * 256 + threadIdx.x;
#pragma unroll
  for (int k = 0; k < 2; ++k) {
    int e = te[2 * t + k];
    int pos = seg[e] + atomicAdd(&meta[8 + e], 1);
    ptok[pos] = t;
    pw[pos] = tw[2 * t + k];
  }
}

// src: float [E][R][C]  ->  dst: bf16 [E][C][R]   (64x64 tiles, 256 thr, vectorized)
__global__ __launch_bounds__(256) void transpose_cvt_kernel(
    const float* __restrict__ src, bf16_t* __restrict__ dst, int R, int C) {
  __shared__ bf16_t tile[64][68];
  int e = blockIdx.z;
  int c0 = blockIdx.x * 64, r0 = blockIdx.y * 64;
  const float* s = src + (size_t)e * R * C;
  bf16_t* d = dst + (size_t)e * R * C;
  int tx = threadIdx.x & 15, ty = threadIdx.x >> 4;
#pragma unroll
  for (int i = 0; i < 4; ++i) {
    int r = ty + i * 16;
    float4 v = *(const float4*)(s + (size_t)(r0 + r) * C + c0 + tx * 4);
    tile[r][tx * 4 + 0] = (bf16_t)v.x;
    tile[r][tx * 4 + 1] = (bf16_t)v.y;
    tile[r][tx * 4 + 2] = (bf16_t)v.z;
    tile[r][tx * 4 + 3] = (bf16_t)v.w;
  }
  __syncthreads();
#pragma unroll
  for (int i = 0; i < 4; ++i) {
    int cc = ty + i * 16;
    bf16x4v o = { tile[tx * 4 + 0][cc], tile[tx * 4 + 1][cc],
                  tile[tx * 4 + 2][cc], tile[tx * 4 + 3][cc] };
    *(bf16x4v*)(d + (size_t)(c0 + cc) * R + r0 + tx * 4) = o;
  }
}

// ======= 256x256 8-wave, 8-phase GEMM (r10 schedule: STAGE phase-first) =======
// LDS 128KiB: A region (buf,half) at (buf*2+h)*16384; B at +65536.
// Swizzle (verified r1-r10): LDS (row, chunk c) holds source chunk c^(row&7).
// Per phase: {STAGE one half-tile (VMEM first) | ds-subtile reads} BAR lgkm(0)
// MFMA(16, setprio) BAR; vmcnt(6) only at ph4/ph8 (r6 ledger).

#define GEMM_PRE()                                                              \
  const int tid = threadIdx.x;                                                  \
  const int lane = tid & 63;                                                    \
  const int wave = tid >> 6;                                                    \
  const int wm = wave >> 2, wn = wave & 3;                                      \
  const int qr = lane >> 4, l16 = lane & 15;                                    \
  const uint32_t aRd0 = (wm * 64 + l16) * 128 + ((qr ^ (l16 & 7)) * 16);        \
  const uint32_t aRd1 = (wm * 64 + l16) * 128 + (((4 + qr) ^ (l16 & 7)) * 16);  \
  const uint32_t bRd0 = (wn * 32 + l16) * 128 + ((qr ^ (l16 & 7)) * 16);        \
  const uint32_t bRd1 = (wn * 32 + l16) * 128 + (((4 + qr) ^ (l16 & 7)) * 16);

#define WAIT_LGKM(N) asm volatile("s_waitcnt lgkmcnt(" #N ")" ::: "memory")
#define WAIT_VM(N)   asm volatile("s_waitcnt vmcnt(" #N ")" ::: "memory")
#define BAR()        __builtin_amdgcn_s_barrier()

#define STAGE_AH(P, H, KT) {                                                    \
  const char* _d = lds + ((P) * 2 + (H)) * 16384 + tid * 16;                    \
  gload_lds16(aSrc[H][0] + (size_t)(KT) * BK, _d);                              \
  gload_lds16(aSrc[H][1] + (size_t)(KT) * BK, _d + 8192); }

#define STAGE_BH(P, H, KT) {                                                    \
  const char* _d = lds + 65536 + ((P) * 2 + (H)) * 16384 + tid * 16;            \
  gload_lds16(bSrc[H][0] + (size_t)(KT) * BK, _d);                              \
  gload_lds16(bSrc[H][1] + (size_t)(KT) * BK, _d + 8192); }

#define LOAD_AH(P, H, AF) {                                                     \
  const char* _p = lds + ((P) * 2 + (H)) * 16384;                               \
  _Pragma("unroll")                                                             \
  for (int mi = 0; mi < 4; ++mi) {                                              \
    AF[mi][0] = *(const bf16x8*)(_p + aRd0 + mi * 2048);                        \
    AF[mi][1] = *(const bf16x8*)(_p + aRd1 + mi * 2048); } }

#define LOAD_BH(P, H, BF) {                                                     \
  const char* _p = lds + 65536 + ((P) * 2 + (H)) * 16384;                       \
  _Pragma("unroll")                                                             \
  for (int ni = 0; ni < 2; ++ni) {                                              \
    BF[ni][0] = *(const bf16x8*)(_p + bRd0 + ni * 2048);                        \
    BF[ni][1] = *(const bf16x8*)(_p + bRd1 + ni * 2048); } }

#define MFMA_Q(AH, BH, AF, BF)                                                  \
  __builtin_amdgcn_s_setprio(1);                                                \
  _Pragma("unroll")                                                             \
  for (int mi = 0; mi < 4; ++mi)                                                \
  _Pragma("unroll")                                                             \
  for (int ni = 0; ni < 2; ++ni) {                                              \
    acc[AH][BH][mi][ni] = __builtin_amdgcn_mfma_f32_16x16x32_bf16(              \
        AF[mi][0], BF[ni][0], acc[AH][BH][mi][ni], 0, 0, 0);                    \
    acc[AH][BH][mi][ni] = __builtin_amdgcn_mfma_f32_16x16x32_bf16(              \
        AF[mi][1], BF[ni][1], acc[AH][BH][mi][ni], 0, 0, 0);                    \
  }                                                                             \
  __builtin_amdgcn_s_setprio(0);

#define ITER8(T, NT)                                                            \
  {                                                                             \
    const int ktO1 = ((T) + 1 < (NT)) ? (T) + 1 : (NT) - 1;                     \
    const int ktE  = ((T) + 2 < (NT)) ? (T) + 2 : (NT) - 1;                     \
    const int ktO  = ((T) + 3 < (NT)) ? (T) + 3 : (NT) - 1;                     \
    /* ph1 (even: A0,B0) — stage first, then ds-reads */                        \
    STAGE_BH(1, 1, ktO1);                                                       \
    LOAD_AH(0, 0, afA); LOAD_BH(0, 0, bf0);                                     \
    WAIT_LGKM(8); BAR(); WAIT_LGKM(0);                                          \
    MFMA_Q(0, 0, afA, bf0); BAR();                                              \
    /* ph2 (even: A1,B0) */                                                     \
    STAGE_AH(0, 0, ktE);                                                        \
    LOAD_AH(0, 1, afB);                                                         \
    BAR(); WAIT_LGKM(0);                                                        \
    MFMA_Q(1, 0, afB, bf0); BAR();                                              \
    /* ph3 (even: A1,B1) */                                                     \
    STAGE_BH(0, 0, ktE);                                                        \
    LOAD_BH(0, 1, bf1);                                                         \
    BAR(); WAIT_LGKM(0);                                                        \
    MFMA_Q(1, 1, afB, bf1); BAR();                                              \
    /* ph4 (even: A0,B1) — register-only MFMA */                                \
    STAGE_AH(0, 1, ktE);                                                        \
    BAR();                                                                      \
    MFMA_Q(0, 1, afA, bf1);                                                     \
    WAIT_VM(6); BAR();                                                          \
    /* ph5 (odd: A0,B0) */                                                      \
    STAGE_BH(0, 1, ktE);                                                        \
    LOAD_AH(1, 0, afA); LOAD_BH(1, 0, bf0);                                     \
    WAIT_LGKM(8); BAR(); WAIT_LGKM(0);                                          \
    MFMA_Q(0, 0, afA, bf0); BAR();                                              \
    /* ph6 (odd: A1,B0) */                                                      \
    STAGE_AH(1, 0, ktO);                                                        \
    LOAD_AH(1, 1, afB);                                                         \
    BAR(); WAIT_LGKM(0);                                                        \
    MFMA_Q(1, 0, afB, bf0); BAR();                                              \
    /* ph7 (odd: A1,B1) */                                                      \
    STAGE_BH(1, 0, ktO);                                                        \
    LOAD_BH(1, 1, bf1);                                                         \
    BAR(); WAIT_LGKM(0);                                                        \
    MFMA_Q(1, 1, afB, bf1); BAR();                                              \
    /* ph8 (odd: A0,B1) — register-only MFMA */                                 \
    STAGE_AH(1, 1, ktO);                                                        \
    BAR();                                                                      \
    MFMA_Q(0, 1, afA, bf1);                                                     \
    WAIT_VM(6); BAR();                                                          \
  }

#define KLOOP8(NT)                                                              \
  {                                                                             \
    const int k1 = 1 < (NT) ? 1 : 0;                                            \
    STAGE_AH(0, 0, 0); STAGE_BH(0, 0, 0); STAGE_AH(0, 1, 0); STAGE_BH(0, 1, 0); \
    STAGE_AH(1, 0, k1); STAGE_BH(1, 0, k1); STAGE_AH(1, 1, k1);                 \
    WAIT_VM(6); BAR();                                                          \
  }                                                                             \
  for (int t = 0; t < (NT); t += 2) ITER8(t, NT)

// ---------------- GEMM1: Hb = gelu(gather(Xb) @ W1t^T + b1) ----------------
__global__ __launch_bounds__(512, 2) void gemm1_kernel(
    const bf16_t* __restrict__ Xb, const bf16_t* __restrict__ W1t,
    const float* __restrict__ b1, const int* __restrict__ ptok,
    const int* __restrict__ meta, bf16_t* __restrict__ Hb) {
  __shared__ __align__(16) char lds[131072];
  GEMM_PRE();
  // chunked XCD swizzle, mt-major within chunk
  int b = blockIdx.x;                       // 2176 blocks
  int g = (b & 7) * 272 + (b >> 3);
  const int mt = g >> 4, nt = g & 15;
  const int row0 = mt * 256;
  const int* seg = meta + 16;
  int e = 0;
#pragma unroll
  for (int k = 1; k < NE; ++k) if (row0 >= seg[k]) e = k;
  if (row0 - seg[e] >= meta[e]) return;

  const bf16_t* aSrc[2][2];
  const bf16_t* bSrc[2][2];
#pragma unroll
  for (int h = 0; h < 2; ++h)
#pragma unroll
    for (int j = 0; j < 2; ++j) {
      int idx = j * 512 + tid;
      int rl = idx >> 3, c = idx & 7;
      int cs = c ^ (rl & 7);
      int tok = ptok[row0 + h * 128 + rl];
      if (tok < 0) tok = 0;
      aSrc[h][j] = Xb + (size_t)tok * DIM + cs * 8;
      int brow = nt * 256 + h * 128 + rl;
      bSrc[h][j] = W1t + (size_t)e * HID * DIM + (size_t)brow * DIM + cs * 8;
    }

  f32x4 acc[2][2][4][2] = {};
  bf16x8 afA[4][2], afB[4][2], bf0[2][2], bf1[2][2];
  KLOOP8(DIM / BK);

  // epilogue: + b1, exact gelu, bf16 store (verified r2)
#pragma unroll
  for (int BH_ = 0; BH_ < 2; ++BH_)
#pragma unroll
  for (int ni = 0; ni < 2; ++ni) {
    int col = nt * 256 + BH_ * 128 + wn * 32 + ni * 16 + l16;
    float bv = b1[e * HID + col];
#pragma unroll
    for (int AH_ = 0; AH_ < 2; ++AH_)
#pragma unroll
    for (int mi = 0; mi < 4; ++mi) {
      int r = row0 + AH_ * 128 + wm * 64 + mi * 16 + qr * 4;
#pragma unroll
      for (int j = 0; j < 4; ++j) {
        float v = acc[AH_][BH_][mi][ni][j] + bv;
        float g2 = 0.5f * v * (1.0f + erff(v * 0.70710678118654752f));
        Hb[(size_t)(r + j) * HID + col] = (bf16_t)g2;
      }
    }
  }
}

// -------- GEMM2 (K-split x2): out[tok] += w * (Hb @ W2t^T [+ b2 if ks==0]) --------
__global__ __launch_bounds__(512, 2) void gemm2_kernel(
    const bf16_t* __restrict__ Hb, const bf16_t* __restrict__ W2t,
    const float* __restrict__ b2, const int* __restrict__ ptok,
    const float* __restrict__ pw, const int* __restrict__ meta,
    float* __restrict__ out) {
  __shared__ __align__(16) char lds[131072];
  GEMM_PRE();
  // chunked XCD swizzle over 1088 blocks; split pair (ks=0/1) lands on same XCD
  int b = blockIdx.x;                       // 1088 blocks
  int g = (b & 7) * 136 + (b >> 3);
  const int ks = g & 1;
  const int g2 = g >> 1;                    // [0, 544)
  const int mt = g2 >> 2, nt = g2 & 3;
  const int row0 = mt * 256;
  const int* seg = meta + 16;
  int e = 0;
#pragma unroll
  for (int k = 1; k < NE; ++k) if (row0 >= seg[k]) e = k;
  if (row0 - seg[e] >= meta[e]) return;

  const size_t kOff = (size_t)ks * 2048;    // K-range base (elements)
  const bf16_t* aSrc[2][2];
  const bf16_t* bSrc[2][2];
#pragma unroll
  for (int h = 0; h < 2; ++h)
#pragma unroll
    for (int j = 0; j < 2; ++j) {
      int idx = j * 512 + tid;
      int rl = idx >> 3, c = idx & 7;
      int cs = c ^ (rl & 7);
      aSrc[h][j] = Hb + (size_t)(row0 + h * 128 + rl) * HID + kOff + cs * 8;
      int brow = nt * 256 + h * 128 + rl;
      bSrc[h][j] = W2t + (size_t)e * DIM * HID + (size_t)brow * HID + kOff + cs * 8;
    }

  f32x4 acc[2][2][4][2] = {};
  bf16x8 afA[4][2], afB[4][2], bf0[2][2], bf1[2][2];
  KLOOP8(2048 / BK);

  // epilogue: gather-combine with atomics; b2 contributed by ks==0 block only
  float bv2[2][2];
#pragma unroll
  for (int BH_ = 0; BH_ < 2; ++BH_)
#pragma unroll
  for (int ni = 0; ni < 2; ++ni)
    bv2[BH_][ni] = (ks == 0)
        ? b2[e * DIM + nt * 256 + BH_ * 128 + wn * 32 + ni * 16 + l16]
        : 0.0f;

#pragma unroll
  for (int AH_ = 0; AH_ < 2; ++AH_)
#pragma unroll
  for (int mi = 0; mi < 4; ++mi) {
    int r = row0 + AH_ * 128 + wm * 64 + mi * 16 + qr * 4;
    int tk[4]; float wv[4];
#pragma unroll
    for (int j = 0; j < 4; ++j) { tk[j] = ptok[r + j]; wv[j] = pw[r + j]; }
#pragma unroll
    for (int BH_ = 0; BH_ < 2; ++BH_)
#pragma unroll
    for (int ni = 0; ni < 2; ++ni) {
      int col = nt * 256 + BH_ * 128 + wn * 32 + ni * 16 + l16;
#pragma unroll
      for (int j = 0; j < 4; ++j) {
        if (tk[j] >= 0)
          atomicAdd(out + (size_t)tk[j] * DIM + col,
                    wv[j] * (acc[AH_][BH_][mi][ni][j] + bv2[BH_][ni]));
      }
    }
  }
}

extern "C" void kernel_launch(void* const* d_in, const int* in_sizes, int n_in,
                              void* d_out, int out_size, void* d_ws, size_t ws_size,
                              hipStream_t stream) {
  const float* x    = (const float*)d_in[0];
  const float* rw   = (const float*)d_in[1];
  const float* w1   = (const float*)d_in[2];
  const float* b1   = (const float*)d_in[3];
  const float* w2   = (const float*)d_in[4];
  const float* b2   = (const float*)d_in[5];
  const float* bias = (const float*)d_in[6];
  float* out    = (float*)d_out;
  float* logits = out + (size_t)T_TOK * DIM;

  // workspace layout (bytes). W1t/W2t OVERLAY (transpose w2 after gemm1).
  const size_t XB_OFF = 0;                         // bf16 [T][D]      33,554,432
  const size_t WT_OFF = 33554432;                  // bf16 [E][*][*]   67,108,864 (shared)
  const size_t HB_OFF = 100663296;                 // bf16 [NSLOT][H] 285,212,672
  const size_t PT_OFF = 385875968;                 // int  [NSLOT]
  const size_t PW_OFF = 386015232;                 // f32  [NSLOT]
  const size_t TE_OFF = 386154496;                 // int  [T*2]
  const size_t TW_OFF = 386285568;                 // f32  [T*2]
  const size_t MT_OFF = 386416640;                 // int  [32]
  const size_t WS_NEEDED = MT_OFF + 128;
  if (ws_size < WS_NEEDED) return;

  char* ws = (char*)d_ws;
  bf16_t* Xb  = (bf16_t*)(ws + XB_OFF);
  bf16_t* Wt  = (bf16_t*)(ws + WT_OFF);
  bf16_t* Hb  = (bf16_t*)(ws + HB_OFF);
  int*    ptok= (int*)  (ws + PT_OFF);
  float*  pwv = (float*)(ws + PW_OFF);
  int*    te  = (int*)  (ws + TE_OFF);
  float*  tw  = (float*)(ws + TW_OFF);
  int*    meta= (int*)  (ws + MT_OFF);

  setup_kernel<<<2048, 256, 0, stream>>>(ptok, meta, out, bias);
  router_kernel<<<T_TOK / 4, 256, 0, stream>>>(x, rw, logits, meta, te, tw, Xb);
  scatter_kernel<<<T_TOK / 256, 256, 0, stream>>>(te, tw, meta, ptok, pwv);
  // W1 transpose: [E][D][H] -> [E][H][D]
  transpose_cvt_kernel<<<dim3(HID / 64, DIM / 64, NE), 256, 0, stream>>>(w1, Wt, DIM, HID);
  gemm1_kernel<<<2176, 512, 0, stream>>>(Xb, Wt, b1, ptok, meta, Hb);
  // W2 transpose into the SAME buffer (gemm1 done reading W1t; stream serializes)
  transpose_cvt_kernel<<<dim3(DIM / 64, HID / 64, NE), 256, 0, stream>>>(w2, Wt, HID, DIM);
  gemm2_kernel<<<1088, 512, 0, stream>>>(Hb, Wt, b2, ptok, pwv, meta, out);
}

// Round 12
// 1417.581 us; speedup vs baseline: 1.0174x; 1.0174x over previous
//
#include <hip/hip_runtime.h>
#include <hip/hip_bf16.h>
#include <cstdint>
#include <cstddef>

#define T_TOK 16384
#define DIM   1024
#define HID   4096
#define NE    8
#define NSLOT 34816   /* 32768 + 8*256 max padded slots (256-aligned segments) */
#define BK 64

typedef __bf16 bf16_t;
typedef __bf16 bf16x8 __attribute__((ext_vector_type(8)));
typedef float  f32x4  __attribute__((ext_vector_type(4)));

__device__ __forceinline__ void gload_lds16(const void* g, const void* l) {
  __builtin_amdgcn_global_load_lds(
      (const __attribute__((address_space(1))) uint32_t*)(uintptr_t)g,
      (__attribute__((address_space(3))) uint32_t*)(uint32_t)(uintptr_t)l,
      16, 0, 0);
}

// meta layout (ints): [0..7]=counts, [8..15]=cursor, [16..24]=seg_base(9)

// setup: ptok=-1, meta=0, out=bias
__global__ __launch_bounds__(256) void setup_kernel(int* __restrict__ ptok,
                                                    int* __restrict__ meta,
                                                    float* __restrict__ out,
                                                    const float* __restrict__ bias) {
  int gi = blockIdx.x * 256 + threadIdx.x;
  if (gi < NSLOT) ptok[gi] = -1;
  if (gi < 16) meta[gi] = 0;
  const int n4 = T_TOK * DIM / 4;
  for (int i = gi; i < n4; i += gridDim.x * 256) {
    ((float4*)out)[i] = ((const float4*)bias)[i & 255];
  }
}

// router + fused f32->bf16 conversion of x into Xb (vectorized 32B/lane)
__global__ __launch_bounds__(256) void router_kernel(
    const float* __restrict__ x, const float* __restrict__ rw,
    float* __restrict__ logits, int* __restrict__ meta,
    int* __restrict__ te, float* __restrict__ tw, bf16_t* __restrict__ Xb) {
  const int lane = threadIdx.x & 63;
  const int t = blockIdx.x * 4 + (threadIdx.x >> 6);
  const float* xr = x + (size_t)t * DIM;
  float acc[NE] = {0.f,0.f,0.f,0.f,0.f,0.f,0.f,0.f};
#pragma unroll
  for (int j = 0; j < 2; ++j) {
    int d0 = j * 512 + lane * 8;
    float4 a = *(const float4*)(xr + d0);
    float4 b = *(const float4*)(xr + d0 + 4);
    bf16x8 o = { (bf16_t)a.x, (bf16_t)a.y, (bf16_t)a.z, (bf16_t)a.w,
                 (bf16_t)b.x, (bf16_t)b.y, (bf16_t)b.z, (bf16_t)b.w };
    *(bf16x8*)(Xb + (size_t)t * DIM + d0) = o;
    float xs[8] = {a.x, a.y, a.z, a.w, b.x, b.y, b.z, b.w};
#pragma unroll
    for (int k = 0; k < 8; ++k) {
      float4 wa = *(const float4*)(rw + (size_t)(d0 + k) * NE);
      float4 wb = *(const float4*)(rw + (size_t)(d0 + k) * NE + 4);
      acc[0] += xs[k] * wa.x; acc[1] += xs[k] * wa.y;
      acc[2] += xs[k] * wa.z; acc[3] += xs[k] * wa.w;
      acc[4] += xs[k] * wb.x; acc[5] += xs[k] * wb.y;
      acc[6] += xs[k] * wb.z; acc[7] += xs[k] * wb.w;
    }
  }
#pragma unroll
  for (int off = 32; off; off >>= 1) {
#pragma unroll
    for (int e = 0; e < NE; ++e) acc[e] += __shfl_down(acc[e], off);
  }
  if (lane == 0) {
    float m = acc[0];
#pragma unroll
    for (int e = 1; e < NE; ++e) m = fmaxf(m, acc[e]);
    float p[NE]; float s = 0.f;
#pragma unroll
    for (int e = 0; e < NE; ++e) { p[e] = expf(acc[e] - m); s += p[e]; }
    float inv = 1.0f / s;
    int e0 = 0;
#pragma unroll
    for (int e = 1; e < NE; ++e) if (p[e] > p[e0]) e0 = e;
    int e1 = (e0 == 0) ? 1 : 0;
#pragma unroll
    for (int e = 0; e < NE; ++e) if (e != e0 && p[e] > p[e1]) e1 = e;
#pragma unroll
    for (int e = 0; e < NE; ++e) logits[(size_t)t * NE + e] = acc[e];
    te[2 * t]     = e0;  te[2 * t + 1] = e1;
    tw[2 * t]     = p[e0] * inv;
    tw[2 * t + 1] = p[e1] * inv;
    atomicAdd(&meta[e0], 1);
    atomicAdd(&meta[e1], 1);
  }
}

// scatter (scan fused): every thread derives seg locally; block0 publishes
__global__ __launch_bounds__(256) void scatter_kernel(
    const int* __restrict__ te, const float* __restrict__ tw,
    int* __restrict__ meta, int* __restrict__ ptok, float* __restrict__ pw) {
  int counts[NE], seg[NE]; int s = 0;
#pragma unroll
  for (int e = 0; e < NE; ++e) counts[e] = meta[e];
#pragma unroll
  for (int e = 0; e < NE; ++e) { seg[e] = s; s += ((counts[e] + 255) / 256) * 256; }
  if (blockIdx.x == 0 && threadIdx.x == 0) {
    int* sg = meta + 16; int a = 0;
    for (int e = 0; e < NE; ++e) { sg[e] = a; a += ((counts[e] + 255) / 256) * 256; }
    sg[NE] = a;
  }
  int t = blockIdx.x * 256 + threadIdx.x;
#pragma unroll
  for (int k = 0; k < 2; ++k) {
    int e = te[2 * t + k];
    int pos = seg[e] + atomicAdd(&meta[8 + e], 1);
    ptok[pos] = t;
    pw[pos] = tw[2 * t + k];
  }
}

// LDS-free register transpose: src float [E][R][C] -> dst bf16 [E][C][R].
// Tile 64(r) x 256(c), 256 threads; thread (tr=t&7, tc=t>>3) owns an 8x8 block.
// Reads: per p, lanes sharing tr read 256B-contiguous row segments (coalesced).
// Writes: per q, 8 lanes of a tc-group write 128B-contiguous output segments.
__global__ __launch_bounds__(256) void transpose_cvt_kernel(
    const float* __restrict__ src, bf16_t* __restrict__ dst, int R, int C) {
  int e = blockIdx.z;
  int c0 = blockIdx.x * 256, r0 = blockIdx.y * 64;
  const float* s = src + (size_t)e * R * C;
  bf16_t* d = dst + (size_t)e * R * C;
  const int tr = threadIdx.x & 7, tc = threadIdx.x >> 3;
  bf16x8 rows[8];
#pragma unroll
  for (int p = 0; p < 8; ++p) {
    const float* rp = s + (size_t)(r0 + 8 * tr + p) * C + c0 + 8 * tc;
    float4 a = *(const float4*)rp;
    float4 b = *(const float4*)(rp + 4);
    bf16x8 v = { (bf16_t)a.x, (bf16_t)a.y, (bf16_t)a.z, (bf16_t)a.w,
                 (bf16_t)b.x, (bf16_t)b.y, (bf16_t)b.z, (bf16_t)b.w };
    rows[p] = v;
  }
#pragma unroll
  for (int q = 0; q < 8; ++q) {
    bf16x8 o = { rows[0][q], rows[1][q], rows[2][q], rows[3][q],
                 rows[4][q], rows[5][q], rows[6][q], rows[7][q] };
    *(bf16x8*)(d + (size_t)(c0 + 8 * tc + q) * R + r0 + 8 * tr) = o;
  }
}

// ======= 256x256 8-wave, 8-phase GEMM (r10 schedule: STAGE phase-first) =======
// LDS 128KiB: A region (buf,half) at (buf*2+h)*16384; B at +65536.
// Swizzle (verified r1-r11): LDS (row, chunk c) holds source chunk c^(row&7).
// Per phase: {STAGE one half-tile (VMEM first) | ds-subtile reads} BAR lgkm(0)
// MFMA(16, setprio) BAR; vmcnt(6) only at ph4/ph8 (r6 ledger).

#define GEMM_PRE()                                                              \
  const int tid = threadIdx.x;                                                  \
  const int lane = tid & 63;                                                    \
  const int wave = tid >> 6;                                                    \
  const int wm = wave >> 2, wn = wave & 3;                                      \
  const int qr = lane >> 4, l16 = lane & 15;                                    \
  const uint32_t aRd0 = (wm * 64 + l16) * 128 + ((qr ^ (l16 & 7)) * 16);        \
  const uint32_t aRd1 = (wm * 64 + l16) * 128 + (((4 + qr) ^ (l16 & 7)) * 16);  \
  const uint32_t bRd0 = (wn * 32 + l16) * 128 + ((qr ^ (l16 & 7)) * 16);        \
  const uint32_t bRd1 = (wn * 32 + l16) * 128 + (((4 + qr) ^ (l16 & 7)) * 16);

#define WAIT_LGKM(N) asm volatile("s_waitcnt lgkmcnt(" #N ")" ::: "memory")
#define WAIT_VM(N)   asm volatile("s_waitcnt vmcnt(" #N ")" ::: "memory")
#define BAR()        __builtin_amdgcn_s_barrier()

#define STAGE_AH(P, H, KT) {                                                    \
  const char* _d = lds + ((P) * 2 + (H)) * 16384 + tid * 16;                    \
  gload_lds16(aSrc[H][0] + (size_t)(KT) * BK, _d);                              \
  gload_lds16(aSrc[H][1] + (size_t)(KT) * BK, _d + 8192); }

#define STAGE_BH(P, H, KT) {                                                    \
  const char* _d = lds + 65536 + ((P) * 2 + (H)) * 16384 + tid * 16;            \
  gload_lds16(bSrc[H][0] + (size_t)(KT) * BK, _d);                              \
  gload_lds16(bSrc[H][1] + (size_t)(KT) * BK, _d + 8192); }

#define LOAD_AH(P, H, AF) {                                                     \
  const char* _p = lds + ((P) * 2 + (H)) * 16384;                               \
  _Pragma("unroll")                                                             \
  for (int mi = 0; mi < 4; ++mi) {                                              \
    AF[mi][0] = *(const bf16x8*)(_p + aRd0 + mi * 2048);                        \
    AF[mi][1] = *(const bf16x8*)(_p + aRd1 + mi * 2048); } }

#define LOAD_BH(P, H, BF) {                                                     \
  const char* _p = lds + 65536 + ((P) * 2 + (H)) * 16384;                       \
  _Pragma("unroll")                                                             \
  for (int ni = 0; ni < 2; ++ni) {                                              \
    BF[ni][0] = *(const bf16x8*)(_p + bRd0 + ni * 2048);                        \
    BF[ni][1] = *(const bf16x8*)(_p + bRd1 + ni * 2048); } }

#define MFMA_Q(AH, BH, AF, BF)                                                  \
  __builtin_amdgcn_s_setprio(1);                                                \
  _Pragma("unroll")                                                             \
  for (int mi = 0; mi < 4; ++mi)                                                \
  _Pragma("unroll")                                                             \
  for (int ni = 0; ni < 2; ++ni) {                                              \
    acc[AH][BH][mi][ni] = __builtin_amdgcn_mfma_f32_16x16x32_bf16(              \
        AF[mi][0], BF[ni][0], acc[AH][BH][mi][ni], 0, 0, 0);                    \
    acc[AH][BH][mi][ni] = __builtin_amdgcn_mfma_f32_16x16x32_bf16(              \
        AF[mi][1], BF[ni][1], acc[AH][BH][mi][ni], 0, 0, 0);                    \
  }                                                                             \
  __builtin_amdgcn_s_setprio(0);

#define ITER8(T, NT)                                                            \
  {                                                                             \
    const int ktO1 = ((T) + 1 < (NT)) ? (T) + 1 : (NT) - 1;                     \
    const int ktE  = ((T) + 2 < (NT)) ? (T) + 2 : (NT) - 1;                     \
    const int ktO  = ((T) + 3 < (NT)) ? (T) + 3 : (NT) - 1;                     \
    /* ph1 (even: A0,B0) — stage first, then ds-reads */                        \
    STAGE_BH(1, 1, ktO1);                                                       \
    LOAD_AH(0, 0, afA); LOAD_BH(0, 0, bf0);                                     \
    WAIT_LGKM(8); BAR(); WAIT_LGKM(0);                                          \
    MFMA_Q(0, 0, afA, bf0); BAR();                                              \
    /* ph2 (even: A1,B0) */                                                     \
    STAGE_AH(0, 0, ktE);                                                        \
    LOAD_AH(0, 1, afB);                                                         \
    BAR(); WAIT_LGKM(0);                                                        \
    MFMA_Q(1, 0, afB, bf0); BAR();                                              \
    /* ph3 (even: A1,B1) */                                                     \
    STAGE_BH(0, 0, ktE);                                                        \
    LOAD_BH(0, 1, bf1);                                                         \
    BAR(); WAIT_LGKM(0);                                                        \
    MFMA_Q(1, 1, afB, bf1); BAR();                                              \
    /* ph4 (even: A0,B1) — register-only MFMA */                                \
    STAGE_AH(0, 1, ktE);                                                        \
    BAR();                                                                      \
    MFMA_Q(0, 1, afA, bf1);                                                     \
    WAIT_VM(6); BAR();                                                          \
    /* ph5 (odd: A0,B0) */                                                      \
    STAGE_BH(0, 1, ktE);                                                        \
    LOAD_AH(1, 0, afA); LOAD_BH(1, 0, bf0);                                     \
    WAIT_LGKM(8); BAR(); WAIT_LGKM(0);                                          \
    MFMA_Q(0, 0, afA, bf0); BAR();                                              \
    /* ph6 (odd: A1,B0) */                                                      \
    STAGE_AH(1, 0, ktO);                                                        \
    LOAD_AH(1, 1, afB);                                                         \
    BAR(); WAIT_LGKM(0);                                                        \
    MFMA_Q(1, 0, afB, bf0); BAR();                                              \
    /* ph7 (odd: A1,B1) */                                                      \
    STAGE_BH(1, 0, ktO);                                                        \
    LOAD_BH(1, 1, bf1);                                                         \
    BAR(); WAIT_LGKM(0);                                                        \
    MFMA_Q(1, 1, afB, bf1); BAR();                                              \
    /* ph8 (odd: A0,B1) — register-only MFMA */                                 \
    STAGE_AH(1, 1, ktO);                                                        \
    BAR();                                                                      \
    MFMA_Q(0, 1, afA, bf1);                                                     \
    WAIT_VM(6); BAR();                                                          \
  }

#define KLOOP8(NT)                                                              \
  {                                                                             \
    const int k1 = 1 < (NT) ? 1 : 0;                                            \
    STAGE_AH(0, 0, 0); STAGE_BH(0, 0, 0); STAGE_AH(0, 1, 0); STAGE_BH(0, 1, 0); \
    STAGE_AH(1, 0, k1); STAGE_BH(1, 0, k1); STAGE_AH(1, 1, k1);                 \
    WAIT_VM(6); BAR();                                                          \
  }                                                                             \
  for (int t = 0; t < (NT); t += 2) ITER8(t, NT)

// ---------------- GEMM1: Hb = gelu(gather(Xb) @ W1t^T + b1) ----------------
__global__ __launch_bounds__(512, 2) void gemm1_kernel(
    const bf16_t* __restrict__ Xb, const bf16_t* __restrict__ W1t,
    const float* __restrict__ b1, const int* __restrict__ ptok,
    const int* __restrict__ meta, bf16_t* __restrict__ Hb) {
  __shared__ __align__(16) char lds[131072];
  GEMM_PRE();
  // chunked XCD swizzle, mt-major within chunk
  int b = blockIdx.x;                       // 2176 blocks
  int g = (b & 7) * 272 + (b >> 3);
  const int mt = g >> 4, nt = g & 15;
  const int row0 = mt * 256;
  const int* seg = meta + 16;
  int e = 0;
#pragma unroll
  for (int k = 1; k < NE; ++k) if (row0 >= seg[k]) e = k;
  if (row0 - seg[e] >= meta[e]) return;

  const bf16_t* aSrc[2][2];
  const bf16_t* bSrc[2][2];
#pragma unroll
  for (int h = 0; h < 2; ++h)
#pragma unroll
    for (int j = 0; j < 2; ++j) {
      int idx = j * 512 + tid;
      int rl = idx >> 3, c = idx & 7;
      int cs = c ^ (rl & 7);
      int tok = ptok[row0 + h * 128 + rl];
      if (tok < 0) tok = 0;
      aSrc[h][j] = Xb + (size_t)tok * DIM + cs * 8;
      int brow = nt * 256 + h * 128 + rl;
      bSrc[h][j] = W1t + (size_t)e * HID * DIM + (size_t)brow * DIM + cs * 8;
    }

  f32x4 acc[2][2][4][2] = {};
  bf16x8 afA[4][2], afB[4][2], bf0[2][2], bf1[2][2];
  KLOOP8(DIM / BK);

  // epilogue: + b1, exact gelu, bf16 store (verified r2)
#pragma unroll
  for (int BH_ = 0; BH_ < 2; ++BH_)
#pragma unroll
  for (int ni = 0; ni < 2; ++ni) {
    int col = nt * 256 + BH_ * 128 + wn * 32 + ni * 16 + l16;
    float bv = b1[e * HID + col];
#pragma unroll
    for (int AH_ = 0; AH_ < 2; ++AH_)
#pragma unroll
    for (int mi = 0; mi < 4; ++mi) {
      int r = row0 + AH_ * 128 + wm * 64 + mi * 16 + qr * 4;
#pragma unroll
      for (int j = 0; j < 4; ++j) {
        float v = acc[AH_][BH_][mi][ni][j] + bv;
        float g2 = 0.5f * v * (1.0f + erff(v * 0.70710678118654752f));
        Hb[(size_t)(r + j) * HID + col] = (bf16_t)g2;
      }
    }
  }
}

// ---------------- GEMM2: out[tok] += w * (Hb @ W2t^T + b2) ----------------
__global__ __launch_bounds__(512, 2) void gemm2_kernel(
    const bf16_t* __restrict__ Hb, const bf16_t* __restrict__ W2t,
    const float* __restrict__ b2, const int* __restrict__ ptok,
    const float* __restrict__ pw, const int* __restrict__ meta,
    float* __restrict__ out) {
  __shared__ __align__(16) char lds[131072];
  GEMM_PRE();
  // chunked XCD swizzle, mt-major
  int b = blockIdx.x;                       // 544 blocks
  int g = (b & 7) * 68 + (b >> 3);
  const int mt = g >> 2, nt = g & 3;
  const int row0 = mt * 256;
  const int* seg = meta + 16;
  int e = 0;
#pragma unroll
  for (int k = 1; k < NE; ++k) if (row0 >= seg[k]) e = k;
  if (row0 - seg[e] >= meta[e]) return;

  const bf16_t* aSrc[2][2];
  const bf16_t* bSrc[2][2];
#pragma unroll
  for (int h = 0; h < 2; ++h)
#pragma unroll
    for (int j = 0; j < 2; ++j) {
      int idx = j * 512 + tid;
      int rl = idx >> 3, c = idx & 7;
      int cs = c ^ (rl & 7);
      aSrc[h][j] = Hb + (size_t)(row0 + h * 128 + rl) * HID + cs * 8;
      int brow = nt * 256 + h * 128 + rl;
      bSrc[h][j] = W2t + (size_t)e * DIM * HID + (size_t)brow * HID + cs * 8;
    }

  f32x4 acc[2][2][4][2] = {};
  bf16x8 afA[4][2], afB[4][2], bf0[2][2], bf1[2][2];
  KLOOP8(HID / BK);

  // epilogue: gather-combine with atomics (verified r2)
  float bv2[2][2];
#pragma unroll
  for (int BH_ = 0; BH_ < 2; ++BH_)
#pragma unroll
  for (int ni = 0; ni < 2; ++ni)
    bv2[BH_][ni] = b2[e * DIM + nt * 256 + BH_ * 128 + wn * 32 + ni * 16 + l16];

#pragma unroll
  for (int AH_ = 0; AH_ < 2; ++AH_)
#pragma unroll
  for (int mi = 0; mi < 4; ++mi) {
    int r = row0 + AH_ * 128 + wm * 64 + mi * 16 + qr * 4;
    int tk[4]; float wv[4];
#pragma unroll
    for (int j = 0; j < 4; ++j) { tk[j] = ptok[r + j]; wv[j] = pw[r + j]; }
#pragma unroll
    for (int BH_ = 0; BH_ < 2; ++BH_)
#pragma unroll
    for (int ni = 0; ni < 2; ++ni) {
      int col = nt * 256 + BH_ * 128 + wn * 32 + ni * 16 + l16;
#pragma unroll
      for (int j = 0; j < 4; ++j) {
        if (tk[j] >= 0)
          atomicAdd(out + (size_t)tk[j] * DIM + col,
                    wv[j] * (acc[AH_][BH_][mi][ni][j] + bv2[BH_][ni]));
      }
    }
  }
}

extern "C" void kernel_launch(void* const* d_in, const int* in_sizes, int n_in,
                              void* d_out, int out_size, void* d_ws, size_t ws_size,
                              hipStream_t stream) {
  const float* x    = (const float*)d_in[0];
  const float* rw   = (const float*)d_in[1];
  const float* w1   = (const float*)d_in[2];
  const float* b1   = (const float*)d_in[3];
  const float* w2   = (const float*)d_in[4];
  const float* b2   = (const float*)d_in[5];
  const float* bias = (const float*)d_in[6];
  float* out    = (float*)d_out;
  float* logits = out + (size_t)T_TOK * DIM;

  // workspace layout (bytes). W1t/W2t OVERLAY (transpose w2 after gemm1).
  const size_t XB_OFF = 0;                         // bf16 [T][D]      33,554,432
  const size_t WT_OFF = 33554432;                  // bf16 [E][*][*]   67,108,864 (shared)
  const size_t HB_OFF = 100663296;                 // bf16 [NSLOT][H] 285,212,672
  const size_t PT_OFF = 385875968;                 // int  [NSLOT]
  const size_t PW_OFF = 386015232;                 // f32  [NSLOT]
  const size_t TE_OFF = 386154496;                 // int  [T*2]
  const size_t TW_OFF = 386285568;                 // f32  [T*2]
  const size_t MT_OFF = 386416640;                 // int  [32]
  const size_t WS_NEEDED = MT_OFF + 128;
  if (ws_size < WS_NEEDED) return;

  char* ws = (char*)d_ws;
  bf16_t* Xb  = (bf16_t*)(ws + XB_OFF);
  bf16_t* Wt  = (bf16_t*)(ws + WT_OFF);
  bf16_t* Hb  = (bf16_t*)(ws + HB_OFF);
  int*    ptok= (int*)  (ws + PT_OFF);
  float*  pwv = (float*)(ws + PW_OFF);
  int*    te  = (int*)  (ws + TE_OFF);
  float*  tw  = (float*)(ws + TW_OFF);
  int*    meta= (int*)  (ws + MT_OFF);

  setup_kernel<<<2048, 256, 0, stream>>>(ptok, meta, out, bias);
  router_kernel<<<T_TOK / 4, 256, 0, stream>>>(x, rw, logits, meta, te, tw, Xb);
  scatter_kernel<<<T_TOK / 256, 256, 0, stream>>>(te, tw, meta, ptok, pwv);
  // W1 transpose: [E][D][H] -> [E][H][D]  (R=DIM, C=HID)
  transpose_cvt_kernel<<<dim3(HID / 256, DIM / 64, NE), 256, 0, stream>>>(w1, Wt, DIM, HID);
  gemm1_kernel<<<2176, 512, 0, stream>>>(Xb, Wt, b1, ptok, meta, Hb);
  // W2 transpose into the SAME buffer (gemm1 done reading W1t; stream serializes)
  transpose_cvt_kernel<<<dim3(DIM / 256, HID / 64, NE), 256, 0, stream>>>(w2, Wt, HID, DIM);
  gemm2_kernel<<<544, 512, 0, stream>>>(Hb, Wt, b2, ptok, pwv, meta, out);
}

// Round 13
// 1021.429 us; speedup vs baseline: 1.4119x; 1.3878x over previous
//
#include <hip/hip_runtime.h>
#include <hip/hip_bf16.h>
#include <cstdint>
#include <cstddef>

#define T_TOK 16384
#define DIM   1024
#define HID   4096
#define NE    8
#define NSLOT 34816   /* 32768 + 8*256 max padded slots (256-aligned segments) */
#define BK 64

typedef __bf16 bf16_t;
typedef __bf16 bf16x8 __attribute__((ext_vector_type(8)));
typedef float  f32x4  __attribute__((ext_vector_type(4)));

__device__ __forceinline__ void gload_lds16(const void* g, const void* l) {
  __builtin_amdgcn_global_load_lds(
      (const __attribute__((address_space(1))) uint32_t*)(uintptr_t)g,
      (__attribute__((address_space(3))) uint32_t*)(uint32_t)(uintptr_t)l,
      16, 0, 0);
}

// meta layout (ints): [0..7]=counts, [8..15]=cursor, [16..23]=seg_base

// router + fused: f32->bf16 x conversion, ptok=-1 init, out=bias init,
// cursor zeroing. All consumed only by LATER kernels (boundary-ordered).
__global__ __launch_bounds__(256) void router_kernel(
    const float* __restrict__ x, const float* __restrict__ rw,
    float* __restrict__ logits, int* __restrict__ meta,
    int* __restrict__ te, float* __restrict__ tw, bf16_t* __restrict__ Xb,
    int* __restrict__ ptok, float* __restrict__ out,
    const float* __restrict__ bias) {
  int gi = blockIdx.x * 256 + threadIdx.x;
  if (gi < NSLOT) ptok[gi] = -1;
  if (gi < 8) meta[8 + gi] = 0;
  const int n4 = T_TOK * DIM / 4;
  for (int i = gi; i < n4; i += gridDim.x * 256) {
    ((float4*)out)[i] = ((const float4*)bias)[i & 255];
  }

  const int lane = threadIdx.x & 63;
  const int t = blockIdx.x * 4 + (threadIdx.x >> 6);
  const float* xr = x + (size_t)t * DIM;
  float acc[NE] = {0.f,0.f,0.f,0.f,0.f,0.f,0.f,0.f};
#pragma unroll
  for (int j = 0; j < 2; ++j) {
    int d0 = j * 512 + lane * 8;
    float4 a = *(const float4*)(xr + d0);
    float4 b = *(const float4*)(xr + d0 + 4);
    bf16x8 o = { (bf16_t)a.x, (bf16_t)a.y, (bf16_t)a.z, (bf16_t)a.w,
                 (bf16_t)b.x, (bf16_t)b.y, (bf16_t)b.z, (bf16_t)b.w };
    *(bf16x8*)(Xb + (size_t)t * DIM + d0) = o;
    float xs[8] = {a.x, a.y, a.z, a.w, b.x, b.y, b.z, b.w};
#pragma unroll
    for (int k = 0; k < 8; ++k) {
      float4 wa = *(const float4*)(rw + (size_t)(d0 + k) * NE);
      float4 wb = *(const float4*)(rw + (size_t)(d0 + k) * NE + 4);
      acc[0] += xs[k] * wa.x; acc[1] += xs[k] * wa.y;
      acc[2] += xs[k] * wa.z; acc[3] += xs[k] * wa.w;
      acc[4] += xs[k] * wb.x; acc[5] += xs[k] * wb.y;
      acc[6] += xs[k] * wb.z; acc[7] += xs[k] * wb.w;
    }
  }
#pragma unroll
  for (int off = 32; off; off >>= 1) {
#pragma unroll
    for (int e = 0; e < NE; ++e) acc[e] += __shfl_down(acc[e], off);
  }
  if (lane == 0) {
    float m = acc[0];
#pragma unroll
    for (int e = 1; e < NE; ++e) m = fmaxf(m, acc[e]);
    float p[NE]; float s = 0.f;
#pragma unroll
    for (int e = 0; e < NE; ++e) { p[e] = expf(acc[e] - m); s += p[e]; }
    float inv = 1.0f / s;
    int e0 = 0;
#pragma unroll
    for (int e = 1; e < NE; ++e) if (p[e] > p[e0]) e0 = e;
    int e1 = (e0 == 0) ? 1 : 0;
#pragma unroll
    for (int e = 0; e < NE; ++e) if (e != e0 && p[e] > p[e1]) e1 = e;
#pragma unroll
    for (int e = 0; e < NE; ++e) logits[(size_t)t * NE + e] = acc[e];
    te[2 * t]     = e0;  te[2 * t + 1] = e1;
    tw[2 * t]     = p[e0] * inv;
    tw[2 * t + 1] = p[e1] * inv;
  }
}

// scatter: each block independently recomputes global counts (compare-accum
// histogram over te), derives 256-aligned segments, then places its own 512
// entries via LDS-aggregated cursor atomics (8 global atomics/block).
__global__ __launch_bounds__(256) void scatter_kernel(
    const int* __restrict__ te, const float* __restrict__ tw,
    int* __restrict__ meta, int* __restrict__ ptok, float* __restrict__ pw) {
  __shared__ int gcnt[8], sseg[8], gbase[8], lcnt[8];
  const int t0 = threadIdx.x;
  if (t0 < 8) { gcnt[t0] = 0; lcnt[t0] = 0; }
  __syncthreads();
  int h0=0,h1=0,h2=0,h3=0,h4=0,h5=0,h6=0,h7=0;
  for (int i = t0; i < 2 * T_TOK; i += 256) {
    int e = te[i];
    h0 += (e == 0); h1 += (e == 1); h2 += (e == 2); h3 += (e == 3);
    h4 += (e == 4); h5 += (e == 5); h6 += (e == 6); h7 += (e == 7);
  }
  atomicAdd(&gcnt[0], h0); atomicAdd(&gcnt[1], h1);
  atomicAdd(&gcnt[2], h2); atomicAdd(&gcnt[3], h3);
  atomicAdd(&gcnt[4], h4); atomicAdd(&gcnt[5], h5);
  atomicAdd(&gcnt[6], h6); atomicAdd(&gcnt[7], h7);
  __syncthreads();
  if (t0 < 8) {
    int s2 = 0;
#pragma unroll
    for (int e2 = 0; e2 < 8; ++e2) {
      int p = (gcnt[e2] + 255) & ~255;
      s2 += (e2 < t0) ? p : 0;
    }
    sseg[t0] = s2;
    if (blockIdx.x == 0) { meta[t0] = gcnt[t0]; meta[16 + t0] = s2; }
  }
  // local placement (order within a segment is irrelevant)
  int t = blockIdx.x * 256 + t0;
  int e0 = te[2 * t], e1 = te[2 * t + 1];
  int lp0 = atomicAdd(&lcnt[e0], 1);
  int lp1 = atomicAdd(&lcnt[e1], 1);
  __syncthreads();
  if (t0 < 8) gbase[t0] = atomicAdd(&meta[8 + t0], lcnt[t0]);
  __syncthreads();
  int pos0 = sseg[e0] + gbase[e0] + lp0;
  int pos1 = sseg[e1] + gbase[e1] + lp1;
  ptok[pos0] = t;  pw[pos0] = tw[2 * t];
  ptok[pos1] = t;  pw[pos1] = tw[2 * t + 1];
}

// LDS-free register transpose tile: src float RxC -> dst bf16 CxR (r12-verified)
__device__ __forceinline__ void tr_tile(const float* __restrict__ s,
                                        bf16_t* __restrict__ d,
                                        int R, int C, int c0, int r0) {
  const int tr = threadIdx.x & 7, tc = threadIdx.x >> 3;
  bf16x8 rows[8];
#pragma unroll
  for (int p = 0; p < 8; ++p) {
    const float* rp = s + (size_t)(r0 + 8 * tr + p) * C + c0 + 8 * tc;
    float4 a = *(const float4*)rp;
    float4 b = *(const float4*)(rp + 4);
    bf16x8 v = { (bf16_t)a.x, (bf16_t)a.y, (bf16_t)a.z, (bf16_t)a.w,
                 (bf16_t)b.x, (bf16_t)b.y, (bf16_t)b.z, (bf16_t)b.w };
    rows[p] = v;
  }
#pragma unroll
  for (int q = 0; q < 8; ++q) {
    bf16x8 o = { rows[0][q], rows[1][q], rows[2][q], rows[3][q],
                 rows[4][q], rows[5][q], rows[6][q], rows[7][q] };
    *(bf16x8*)(d + (size_t)(c0 + 8 * tc + q) * R + r0 + 8 * tr) = o;
  }
}

// big-ws path: both weights transposed in ONE launch (separate buffers)
__global__ __launch_bounds__(256) void transpose_both_kernel(
    const float* __restrict__ w1, const float* __restrict__ w2,
    bf16_t* __restrict__ W1t, bf16_t* __restrict__ W2t) {
  int b = blockIdx.x;
  if (b < 2048) {
    int e = b >> 8, rem = b & 255;
    tr_tile(w1 + (size_t)e * DIM * HID, W1t + (size_t)e * DIM * HID,
            DIM, HID, (rem & 15) * 256, (rem >> 4) * 64);
  } else {
    b -= 2048;
    int e = b >> 8, rem = b & 255;
    tr_tile(w2 + (size_t)e * DIM * HID, W2t + (size_t)e * DIM * HID,
            HID, DIM, (rem & 3) * 256, (rem >> 2) * 64);
  }
}

// fallback path: single-matrix transpose (r12)
__global__ __launch_bounds__(256) void transpose_cvt_kernel(
    const float* __restrict__ src, bf16_t* __restrict__ dst, int R, int C) {
  int e = blockIdx.z;
  tr_tile(src + (size_t)e * R * C, dst + (size_t)e * R * C,
          R, C, blockIdx.x * 256, blockIdx.y * 64);
}

// ======= 256x256 8-wave, 8-phase GEMM (r10/r12 schedule, byte-identical) =======
#define GEMM_PRE()                                                              \
  const int tid = threadIdx.x;                                                  \
  const int lane = tid & 63;                                                    \
  const int wave = tid >> 6;                                                    \
  const int wm = wave >> 2, wn = wave & 3;                                      \
  const int qr = lane >> 4, l16 = lane & 15;                                    \
  const uint32_t aRd0 = (wm * 64 + l16) * 128 + ((qr ^ (l16 & 7)) * 16);        \
  const uint32_t aRd1 = (wm * 64 + l16) * 128 + (((4 + qr) ^ (l16 & 7)) * 16);  \
  const uint32_t bRd0 = (wn * 32 + l16) * 128 + ((qr ^ (l16 & 7)) * 16);        \
  const uint32_t bRd1 = (wn * 32 + l16) * 128 + (((4 + qr) ^ (l16 & 7)) * 16);

#define WAIT_LGKM(N) asm volatile("s_waitcnt lgkmcnt(" #N ")" ::: "memory")
#define WAIT_VM(N)   asm volatile("s_waitcnt vmcnt(" #N ")" ::: "memory")
#define BAR()        __builtin_amdgcn_s_barrier()

#define STAGE_AH(P, H, KT) {                                                    \
  const char* _d = lds + ((P) * 2 + (H)) * 16384 + tid * 16;                    \
  gload_lds16(aSrc[H][0] + (size_t)(KT) * BK, _d);                              \
  gload_lds16(aSrc[H][1] + (size_t)(KT) * BK, _d + 8192); }

#define STAGE_BH(P, H, KT) {                                                    \
  const char* _d = lds + 65536 + ((P) * 2 + (H)) * 16384 + tid * 16;            \
  gload_lds16(bSrc[H][0] + (size_t)(KT) * BK, _d);                              \
  gload_lds16(bSrc[H][1] + (size_t)(KT) * BK, _d + 8192); }

#define LOAD_AH(P, H, AF) {                                                     \
  const char* _p = lds + ((P) * 2 + (H)) * 16384;                               \
  _Pragma("unroll")                                                             \
  for (int mi = 0; mi < 4; ++mi) {                                              \
    AF[mi][0] = *(const bf16x8*)(_p + aRd0 + mi * 2048);                        \
    AF[mi][1] = *(const bf16x8*)(_p + aRd1 + mi * 2048); } }

#define LOAD_BH(P, H, BF) {                                                     \
  const char* _p = lds + 65536 + ((P) * 2 + (H)) * 16384;                       \
  _Pragma("unroll")                                                             \
  for (int ni = 0; ni < 2; ++ni) {                                              \
    BF[ni][0] = *(const bf16x8*)(_p + bRd0 + ni * 2048);                        \
    BF[ni][1] = *(const bf16x8*)(_p + bRd1 + ni * 2048); } }

#define MFMA_Q(AH, BH, AF, BF)                                                  \
  __builtin_amdgcn_s_setprio(1);                                                \
  _Pragma("unroll")                                                             \
  for (int mi = 0; mi < 4; ++mi)                                                \
  _Pragma("unroll")                                                             \
  for (int ni = 0; ni < 2; ++ni) {                                              \
    acc[AH][BH][mi][ni] = __builtin_amdgcn_mfma_f32_16x16x32_bf16(              \
        AF[mi][0], BF[ni][0], acc[AH][BH][mi][ni], 0, 0, 0);                    \
    acc[AH][BH][mi][ni] = __builtin_amdgcn_mfma_f32_16x16x32_bf16(              \
        AF[mi][1], BF[ni][1], acc[AH][BH][mi][ni], 0, 0, 0);                    \
  }                                                                             \
  __builtin_amdgcn_s_setprio(0);

#define ITER8(T, NT)                                                            \
  {                                                                             \
    const int ktO1 = ((T) + 1 < (NT)) ? (T) + 1 : (NT) - 1;                     \
    const int ktE  = ((T) + 2 < (NT)) ? (T) + 2 : (NT) - 1;                     \
    const int ktO  = ((T) + 3 < (NT)) ? (T) + 3 : (NT) - 1;                     \
    STAGE_BH(1, 1, ktO1);                                                       \
    LOAD_AH(0, 0, afA); LOAD_BH(0, 0, bf0);                                     \
    WAIT_LGKM(8); BAR(); WAIT_LGKM(0);                                          \
    MFMA_Q(0, 0, afA, bf0); BAR();                                              \
    STAGE_AH(0, 0, ktE);                                                        \
    LOAD_AH(0, 1, afB);                                                         \
    BAR(); WAIT_LGKM(0);                                                        \
    MFMA_Q(1, 0, afB, bf0); BAR();                                              \
    STAGE_BH(0, 0, ktE);                                                        \
    LOAD_BH(0, 1, bf1);                                                         \
    BAR(); WAIT_LGKM(0);                                                        \
    MFMA_Q(1, 1, afB, bf1); BAR();                                              \
    STAGE_AH(0, 1, ktE);                                                        \
    BAR();                                                                      \
    MFMA_Q(0, 1, afA, bf1);                                                     \
    WAIT_VM(6); BAR();                                                          \
    STAGE_BH(0, 1, ktE);                                                        \
    LOAD_AH(1, 0, afA); LOAD_BH(1, 0, bf0);                                     \
    WAIT_LGKM(8); BAR(); WAIT_LGKM(0);                                          \
    MFMA_Q(0, 0, afA, bf0); BAR();                                              \
    STAGE_AH(1, 0, ktO);                                                        \
    LOAD_AH(1, 1, afB);                                                         \
    BAR(); WAIT_LGKM(0);                                                        \
    MFMA_Q(1, 0, afB, bf0); BAR();                                              \
    STAGE_BH(1, 0, ktO);                                                        \
    LOAD_BH(1, 1, bf1);                                                         \
    BAR(); WAIT_LGKM(0);                                                        \
    MFMA_Q(1, 1, afB, bf1); BAR();                                              \
    STAGE_AH(1, 1, ktO);                                                        \
    BAR();                                                                      \
    MFMA_Q(0, 1, afA, bf1);                                                     \
    WAIT_VM(6); BAR();                                                          \
  }

#define KLOOP8(NT)                                                              \
  {                                                                             \
    const int k1 = 1 < (NT) ? 1 : 0;                                            \
    STAGE_AH(0, 0, 0); STAGE_BH(0, 0, 0); STAGE_AH(0, 1, 0); STAGE_BH(0, 1, 0); \
    STAGE_AH(1, 0, k1); STAGE_BH(1, 0, k1); STAGE_AH(1, 1, k1);                 \
    WAIT_VM(6); BAR();                                                          \
  }                                                                             \
  for (int t = 0; t < (NT); t += 2) ITER8(t, NT)

// ---------------- GEMM1: Hb = gelu(gather(Xb) @ W1t^T + b1) ----------------
__global__ __launch_bounds__(512, 2) void gemm1_kernel(
    const bf16_t* __restrict__ Xb, const bf16_t* __restrict__ W1t,
    const float* __restrict__ b1, const int* __restrict__ ptok,
    const int* __restrict__ meta, bf16_t* __restrict__ Hb) {
  __shared__ __align__(16) char lds[131072];
  GEMM_PRE();
  int b = blockIdx.x;                       // 2176 blocks
  int g = (b & 7) * 272 + (b >> 3);
  const int mt = g >> 4, nt = g & 15;
  const int row0 = mt * 256;
  const int* seg = meta + 16;
  int e = 0;
#pragma unroll
  for (int k = 1; k < NE; ++k) if (row0 >= seg[k]) e = k;
  if (row0 - seg[e] >= meta[e]) return;

  const bf16_t* aSrc[2][2];
  const bf16_t* bSrc[2][2];
#pragma unroll
  for (int h = 0; h < 2; ++h)
#pragma unroll
    for (int j = 0; j < 2; ++j) {
      int idx = j * 512 + tid;
      int rl = idx >> 3, c = idx & 7;
      int cs = c ^ (rl & 7);
      int tok = ptok[row0 + h * 128 + rl];
      if (tok < 0) tok = 0;
      aSrc[h][j] = Xb + (size_t)tok * DIM + cs * 8;
      int brow = nt * 256 + h * 128 + rl;
      bSrc[h][j] = W1t + (size_t)e * HID * DIM + (size_t)brow * DIM + cs * 8;
    }

  f32x4 acc[2][2][4][2] = {};
  bf16x8 afA[4][2], afB[4][2], bf0[2][2], bf1[2][2];
  KLOOP8(DIM / BK);

#pragma unroll
  for (int BH_ = 0; BH_ < 2; ++BH_)
#pragma unroll
  for (int ni = 0; ni < 2; ++ni) {
    int col = nt * 256 + BH_ * 128 + wn * 32 + ni * 16 + l16;
    float bv = b1[e * HID + col];
#pragma unroll
    for (int AH_ = 0; AH_ < 2; ++AH_)
#pragma unroll
    for (int mi = 0; mi < 4; ++mi) {
      int r = row0 + AH_ * 128 + wm * 64 + mi * 16 + qr * 4;
#pragma unroll
      for (int j = 0; j < 4; ++j) {
        float v = acc[AH_][BH_][mi][ni][j] + bv;
        float g2 = 0.5f * v * (1.0f + erff(v * 0.70710678118654752f));
        Hb[(size_t)(r + j) * HID + col] = (bf16_t)g2;
      }
    }
  }
}

// ---------------- GEMM2: out[tok] += w * (Hb @ W2t^T + b2) ----------------
__global__ __launch_bounds__(512, 2) void gemm2_kernel(
    const bf16_t* __restrict__ Hb, const bf16_t* __restrict__ W2t,
    const float* __restrict__ b2, const int* __restrict__ ptok,
    const float* __restrict__ pw, const int* __restrict__ meta,
    float* __restrict__ out) {
  __shared__ __align__(16) char lds[131072];
  GEMM_PRE();
  int b = blockIdx.x;                       // 544 blocks
  int g = (b & 7) * 68 + (b >> 3);
  const int mt = g >> 2, nt = g & 3;
  const int row0 = mt * 256;
  const int* seg = meta + 16;
  int e = 0;
#pragma unroll
  for (int k = 1; k < NE; ++k) if (row0 >= seg[k]) e = k;
  if (row0 - seg[e] >= meta[e]) return;

  const bf16_t* aSrc[2][2];
  const bf16_t* bSrc[2][2];
#pragma unroll
  for (int h = 0; h < 2; ++h)
#pragma unroll
    for (int j = 0; j < 2; ++j) {
      int idx = j * 512 + tid;
      int rl = idx >> 3, c = idx & 7;
      int cs = c ^ (rl & 7);
      aSrc[h][j] = Hb + (size_t)(row0 + h * 128 + rl) * HID + cs * 8;
      int brow = nt * 256 + h * 128 + rl;
      bSrc[h][j] = W2t + (size_t)e * DIM * HID + (size_t)brow * HID + cs * 8;
    }

  f32x4 acc[2][2][4][2] = {};
  bf16x8 afA[4][2], afB[4][2], bf0[2][2], bf1[2][2];
  KLOOP8(HID / BK);

  float bv2[2][2];
#pragma unroll
  for (int BH_ = 0; BH_ < 2; ++BH_)
#pragma unroll
  for (int ni = 0; ni < 2; ++ni)
    bv2[BH_][ni] = b2[e * DIM + nt * 256 + BH_ * 128 + wn * 32 + ni * 16 + l16];

#pragma unroll
  for (int AH_ = 0; AH_ < 2; ++AH_)
#pragma unroll
  for (int mi = 0; mi < 4; ++mi) {
    int r = row0 + AH_ * 128 + wm * 64 + mi * 16 + qr * 4;
    int tk[4]; float wv[4];
#pragma unroll
    for (int j = 0; j < 4; ++j) { tk[j] = ptok[r + j]; wv[j] = pw[r + j]; }
#pragma unroll
    for (int BH_ = 0; BH_ < 2; ++BH_)
#pragma unroll
    for (int ni = 0; ni < 2; ++ni) {
      int col = nt * 256 + BH_ * 128 + wn * 32 + ni * 16 + l16;
#pragma unroll
      for (int j = 0; j < 4; ++j) {
        if (tk[j] >= 0)
          atomicAdd(out + (size_t)tk[j] * DIM + col,
                    wv[j] * (acc[AH_][BH_][mi][ni][j] + bv2[BH_][ni]));
      }
    }
  }
}

extern "C" void kernel_launch(void* const* d_in, const int* in_sizes, int n_in,
                              void* d_out, int out_size, void* d_ws, size_t ws_size,
                              hipStream_t stream) {
  const float* x    = (const float*)d_in[0];
  const float* rw   = (const float*)d_in[1];
  const float* w1   = (const float*)d_in[2];
  const float* b1   = (const float*)d_in[3];
  const float* w2   = (const float*)d_in[4];
  const float* b2   = (const float*)d_in[5];
  const float* bias = (const float*)d_in[6];
  float* out    = (float*)d_out;
  float* logits = out + (size_t)T_TOK * DIM;
  char* ws = (char*)d_ws;

  // big layout: separate W1t/W2t (no overlay) -> 5 launches
  const size_t B_XB  = 0;                    // bf16 [T][D]       33,554,432
  const size_t B_W1T = 33554432;             // bf16 [E][H][D]    67,108,864
  const size_t B_W2T = 100663296;            // bf16 [E][D][H]    67,108,864
  const size_t B_HB  = 167772160;            // bf16 [NSLOT][H]  285,212,672
  const size_t B_PT  = 452984832;            // int  [NSLOT]
  const size_t B_PW  = 453124096;            // f32  [NSLOT]
  const size_t B_TE  = 453263360;            // int  [T*2]
  const size_t B_TW  = 453394432;            // f32  [T*2]
  const size_t B_MT  = 453525504;            // int  [32]
  const size_t NEED_BIG = B_MT + 128;

  // fallback layout (r12, proven): W1t/W2t overlay -> 6 launches
  const size_t F_XB = 0;
  const size_t F_WT = 33554432;
  const size_t F_HB = 100663296;
  const size_t F_PT = 385875968;
  const size_t F_PW = 386015232;
  const size_t F_TE = 386154496;
  const size_t F_TW = 386285568;
  const size_t F_MT = 386416640;
  const size_t NEED_FB = F_MT + 128;

  if (ws_size >= NEED_BIG) {
    bf16_t* Xb  = (bf16_t*)(ws + B_XB);
    bf16_t* W1t = (bf16_t*)(ws + B_W1T);
    bf16_t* W2t = (bf16_t*)(ws + B_W2T);
    bf16_t* Hb  = (bf16_t*)(ws + B_HB);
    int*    ptok= (int*)  (ws + B_PT);
    float*  pwv = (float*)(ws + B_PW);
    int*    te  = (int*)  (ws + B_TE);
    float*  tw  = (float*)(ws + B_TW);
    int*    meta= (int*)  (ws + B_MT);

    router_kernel<<<T_TOK / 4, 256, 0, stream>>>(x, rw, logits, meta, te, tw,
                                                 Xb, ptok, out, bias);
    scatter_kernel<<<T_TOK / 256, 256, 0, stream>>>(te, tw, meta, ptok, pwv);
    transpose_both_kernel<<<4096, 256, 0, stream>>>(w1, w2, W1t, W2t);
    gemm1_kernel<<<2176, 512, 0, stream>>>(Xb, W1t, b1, ptok, meta, Hb);
    gemm2_kernel<<<544, 512, 0, stream>>>(Hb, W2t, b2, ptok, pwv, meta, out);
  } else {
    if (ws_size < NEED_FB) return;
    bf16_t* Xb  = (bf16_t*)(ws + F_XB);
    bf16_t* Wt  = (bf16_t*)(ws + F_WT);
    bf16_t* Hb  = (bf16_t*)(ws + F_HB);
    int*    ptok= (int*)  (ws + F_PT);
    float*  pwv = (float*)(ws + F_PW);
    int*    te  = (int*)  (ws + F_TE);
    float*  tw  = (float*)(ws + F_TW);
    int*    meta= (int*)  (ws + F_MT);

    router_kernel<<<T_TOK / 4, 256, 0, stream>>>(x, rw, logits, meta, te, tw,
                                                 Xb, ptok, out, bias);
    scatter_kernel<<<T_TOK / 256, 256, 0, stream>>>(te, tw, meta, ptok, pwv);
    transpose_cvt_kernel<<<dim3(HID / 256, DIM / 64, NE), 256, 0, stream>>>(w1, Wt, DIM, HID);
    gemm1_kernel<<<2176, 512, 0, stream>>>(Xb, Wt, b1, ptok, meta, Hb);
    transpose_cvt_kernel<<<dim3(DIM / 256, HID / 64, NE), 256, 0, stream>>>(w2, Wt, HID, DIM);
    gemm2_kernel<<<544, 512, 0, stream>>>(Hb, Wt, b2, ptok, pwv, meta, out);
  }
}

// Round 14
// 1009.549 us; speedup vs baseline: 1.4285x; 1.0118x over previous
//
#include <hip/hip_runtime.h>
#include <hip/hip_bf16.h>
#include <cstdint>
#include <cstddef>

#define T_TOK 16384
#define DIM   1024
#define HID   4096
#define NE    8
#define NSLOT 34816   /* 32768 + 8*256 max padded slots (256-aligned segments) */
#define BK 64

typedef __bf16 bf16_t;
typedef __bf16 bf16x8 __attribute__((ext_vector_type(8)));
typedef float  f32x4  __attribute__((ext_vector_type(4)));

__device__ __forceinline__ void gload_lds16(const void* g, const void* l) {
  __builtin_amdgcn_global_load_lds(
      (const __attribute__((address_space(1))) uint32_t*)(uintptr_t)g,
      (__attribute__((address_space(3))) uint32_t*)(uint32_t)(uintptr_t)l,
      16, 0, 0);
}

// meta layout (ints): [0..7]=counts, [8..15]=cursor, [16..23]=seg_base

// router + fused: f32->bf16 x conversion, ptok=-1 init, out=bias init,
// cursor zeroing. All consumed only by LATER kernels (boundary-ordered).
__global__ __launch_bounds__(256) void router_kernel(
    const float* __restrict__ x, const float* __restrict__ rw,
    float* __restrict__ logits, int* __restrict__ meta,
    int* __restrict__ te, float* __restrict__ tw, bf16_t* __restrict__ Xb,
    int* __restrict__ ptok, float* __restrict__ out,
    const float* __restrict__ bias) {
  int gi = blockIdx.x * 256 + threadIdx.x;
  if (gi < NSLOT) ptok[gi] = -1;
  if (gi < 8) meta[8 + gi] = 0;
  const int n4 = T_TOK * DIM / 4;
  for (int i = gi; i < n4; i += gridDim.x * 256) {
    ((float4*)out)[i] = ((const float4*)bias)[i & 255];
  }

  const int lane = threadIdx.x & 63;
  const int t = blockIdx.x * 4 + (threadIdx.x >> 6);
  const float* xr = x + (size_t)t * DIM;
  float acc[NE] = {0.f,0.f,0.f,0.f,0.f,0.f,0.f,0.f};
#pragma unroll
  for (int j = 0; j < 2; ++j) {
    int d0 = j * 512 + lane * 8;
    float4 a = *(const float4*)(xr + d0);
    float4 b = *(const float4*)(xr + d0 + 4);
    bf16x8 o = { (bf16_t)a.x, (bf16_t)a.y, (bf16_t)a.z, (bf16_t)a.w,
                 (bf16_t)b.x, (bf16_t)b.y, (bf16_t)b.z, (bf16_t)b.w };
    *(bf16x8*)(Xb + (size_t)t * DIM + d0) = o;
    float xs[8] = {a.x, a.y, a.z, a.w, b.x, b.y, b.z, b.w};
#pragma unroll
    for (int k = 0; k < 8; ++k) {
      float4 wa = *(const float4*)(rw + (size_t)(d0 + k) * NE);
      float4 wb = *(const float4*)(rw + (size_t)(d0 + k) * NE + 4);
      acc[0] += xs[k] * wa.x; acc[1] += xs[k] * wa.y;
      acc[2] += xs[k] * wa.z; acc[3] += xs[k] * wa.w;
      acc[4] += xs[k] * wb.x; acc[5] += xs[k] * wb.y;
      acc[6] += xs[k] * wb.z; acc[7] += xs[k] * wb.w;
    }
  }
#pragma unroll
  for (int off = 32; off; off >>= 1) {
#pragma unroll
    for (int e = 0; e < NE; ++e) acc[e] += __shfl_down(acc[e], off);
  }
  if (lane == 0) {
    float m = acc[0];
#pragma unroll
    for (int e = 1; e < NE; ++e) m = fmaxf(m, acc[e]);
    float p[NE]; float s = 0.f;
#pragma unroll
    for (int e = 0; e < NE; ++e) { p[e] = expf(acc[e] - m); s += p[e]; }
    float inv = 1.0f / s;
    int e0 = 0;
#pragma unroll
    for (int e = 1; e < NE; ++e) if (p[e] > p[e0]) e0 = e;
    int e1 = (e0 == 0) ? 1 : 0;
#pragma unroll
    for (int e = 0; e < NE; ++e) if (e != e0 && p[e] > p[e1]) e1 = e;
#pragma unroll
    for (int e = 0; e < NE; ++e) logits[(size_t)t * NE + e] = acc[e];
    te[2 * t]     = e0;  te[2 * t + 1] = e1;
    tw[2 * t]     = p[e0] * inv;
    tw[2 * t + 1] = p[e1] * inv;
  }
}

// scatter: each block independently recomputes global counts (compare-accum
// histogram over te), derives 256-aligned segments, then places its own 512
// entries via LDS-aggregated cursor atomics (8 global atomics/block).
__global__ __launch_bounds__(256) void scatter_kernel(
    const int* __restrict__ te, const float* __restrict__ tw,
    int* __restrict__ meta, int* __restrict__ ptok, float* __restrict__ pw) {
  __shared__ int gcnt[8], sseg[8], gbase[8], lcnt[8];
  const int t0 = threadIdx.x;
  if (t0 < 8) { gcnt[t0] = 0; lcnt[t0] = 0; }
  __syncthreads();
  int h0=0,h1=0,h2=0,h3=0,h4=0,h5=0,h6=0,h7=0;
  for (int i = t0; i < 2 * T_TOK; i += 256) {
    int e = te[i];
    h0 += (e == 0); h1 += (e == 1); h2 += (e == 2); h3 += (e == 3);
    h4 += (e == 4); h5 += (e == 5); h6 += (e == 6); h7 += (e == 7);
  }
  atomicAdd(&gcnt[0], h0); atomicAdd(&gcnt[1], h1);
  atomicAdd(&gcnt[2], h2); atomicAdd(&gcnt[3], h3);
  atomicAdd(&gcnt[4], h4); atomicAdd(&gcnt[5], h5);
  atomicAdd(&gcnt[6], h6); atomicAdd(&gcnt[7], h7);
  __syncthreads();
  if (t0 < 8) {
    int s2 = 0;
#pragma unroll
    for (int e2 = 0; e2 < 8; ++e2) {
      int p = (gcnt[e2] + 255) & ~255;
      s2 += (e2 < t0) ? p : 0;
    }
    sseg[t0] = s2;
    if (blockIdx.x == 0) { meta[t0] = gcnt[t0]; meta[16 + t0] = s2; }
  }
  // local placement (order within a segment is irrelevant)
  int t = blockIdx.x * 256 + t0;
  int e0 = te[2 * t], e1 = te[2 * t + 1];
  int lp0 = atomicAdd(&lcnt[e0], 1);
  int lp1 = atomicAdd(&lcnt[e1], 1);
  __syncthreads();
  if (t0 < 8) gbase[t0] = atomicAdd(&meta[8 + t0], lcnt[t0]);
  __syncthreads();
  int pos0 = sseg[e0] + gbase[e0] + lp0;
  int pos1 = sseg[e1] + gbase[e1] + lp1;
  ptok[pos0] = t;  pw[pos0] = tw[2 * t];
  ptok[pos1] = t;  pw[pos1] = tw[2 * t + 1];
}

// LDS-free register transpose tile: src float RxC -> dst bf16 CxR (r12-verified)
__device__ __forceinline__ void tr_tile(const float* __restrict__ s,
                                        bf16_t* __restrict__ d,
                                        int R, int C, int c0, int r0) {
  const int tr = threadIdx.x & 7, tc = threadIdx.x >> 3;
  bf16x8 rows[8];
#pragma unroll
  for (int p = 0; p < 8; ++p) {
    const float* rp = s + (size_t)(r0 + 8 * tr + p) * C + c0 + 8 * tc;
    float4 a = *(const float4*)rp;
    float4 b = *(const float4*)(rp + 4);
    bf16x8 v = { (bf16_t)a.x, (bf16_t)a.y, (bf16_t)a.z, (bf16_t)a.w,
                 (bf16_t)b.x, (bf16_t)b.y, (bf16_t)b.z, (bf16_t)b.w };
    rows[p] = v;
  }
#pragma unroll
  for (int q = 0; q < 8; ++q) {
    bf16x8 o = { rows[0][q], rows[1][q], rows[2][q], rows[3][q],
                 rows[4][q], rows[5][q], rows[6][q], rows[7][q] };
    *(bf16x8*)(d + (size_t)(c0 + 8 * tc + q) * R + r0 + 8 * tr) = o;
  }
}

// big-ws path: both weights transposed in ONE launch (separate buffers)
__global__ __launch_bounds__(256) void transpose_both_kernel(
    const float* __restrict__ w1, const float* __restrict__ w2,
    bf16_t* __restrict__ W1t, bf16_t* __restrict__ W2t) {
  int b = blockIdx.x;
  if (b < 2048) {
    int e = b >> 8, rem = b & 255;
    tr_tile(w1 + (size_t)e * DIM * HID, W1t + (size_t)e * DIM * HID,
            DIM, HID, (rem & 15) * 256, (rem >> 4) * 64);
  } else {
    b -= 2048;
    int e = b >> 8, rem = b & 255;
    tr_tile(w2 + (size_t)e * DIM * HID, W2t + (size_t)e * DIM * HID,
            HID, DIM, (rem & 3) * 256, (rem >> 2) * 64);
  }
}

// fallback path: single-matrix transpose (r12)
__global__ __launch_bounds__(256) void transpose_cvt_kernel(
    const float* __restrict__ src, bf16_t* __restrict__ dst, int R, int C) {
  int e = blockIdx.z;
  tr_tile(src + (size_t)e * R * C, dst + (size_t)e * R * C,
          R, C, blockIdx.x * 256, blockIdx.y * 64);
}

// ======= 256x256 8-wave, 8-phase GEMM (r10/r13 schedule, byte-identical) =======
#define GEMM_PRE()                                                              \
  const int tid = threadIdx.x;                                                  \
  const int lane = tid & 63;                                                    \
  const int wave = tid >> 6;                                                    \
  const int wm = wave >> 2, wn = wave & 3;                                      \
  const int qr = lane >> 4, l16 = lane & 15;                                    \
  const uint32_t aRd0 = (wm * 64 + l16) * 128 + ((qr ^ (l16 & 7)) * 16);        \
  const uint32_t aRd1 = (wm * 64 + l16) * 128 + (((4 + qr) ^ (l16 & 7)) * 16);  \
  const uint32_t bRd0 = (wn * 32 + l16) * 128 + ((qr ^ (l16 & 7)) * 16);        \
  const uint32_t bRd1 = (wn * 32 + l16) * 128 + (((4 + qr) ^ (l16 & 7)) * 16);

#define WAIT_LGKM(N) asm volatile("s_waitcnt lgkmcnt(" #N ")" ::: "memory")
#define WAIT_VM(N)   asm volatile("s_waitcnt vmcnt(" #N ")" ::: "memory")
#define BAR()        __builtin_amdgcn_s_barrier()

#define STAGE_AH(P, H, KT) {                                                    \
  const char* _d = lds + ((P) * 2 + (H)) * 16384 + tid * 16;                    \
  gload_lds16(aSrc[H][0] + (size_t)(KT) * BK, _d);                              \
  gload_lds16(aSrc[H][1] + (size_t)(KT) * BK, _d + 8192); }

#define STAGE_BH(P, H, KT) {                                                    \
  const char* _d = lds + 65536 + ((P) * 2 + (H)) * 16384 + tid * 16;            \
  gload_lds16(bSrc[H][0] + (size_t)(KT) * BK, _d);                              \
  gload_lds16(bSrc[H][1] + (size_t)(KT) * BK, _d + 8192); }

#define LOAD_AH(P, H, AF) {                                                     \
  const char* _p = lds + ((P) * 2 + (H)) * 16384;                               \
  _Pragma("unroll")                                                             \
  for (int mi = 0; mi < 4; ++mi) {                                              \
    AF[mi][0] = *(const bf16x8*)(_p + aRd0 + mi * 2048);                        \
    AF[mi][1] = *(const bf16x8*)(_p + aRd1 + mi * 2048); } }

#define LOAD_BH(P, H, BF) {                                                     \
  const char* _p = lds + 65536 + ((P) * 2 + (H)) * 16384;                       \
  _Pragma("unroll")                                                             \
  for (int ni = 0; ni < 2; ++ni) {                                              \
    BF[ni][0] = *(const bf16x8*)(_p + bRd0 + ni * 2048);                        \
    BF[ni][1] = *(const bf16x8*)(_p + bRd1 + ni * 2048); } }

#define MFMA_Q(AH, BH, AF, BF)                                                  \
  __builtin_amdgcn_s_setprio(1);                                                \
  _Pragma("unroll")                                                             \
  for (int mi = 0; mi < 4; ++mi)                                                \
  _Pragma("unroll")                                                             \
  for (int ni = 0; ni < 2; ++ni) {                                              \
    acc[AH][BH][mi][ni] = __builtin_amdgcn_mfma_f32_16x16x32_bf16(              \
        AF[mi][0], BF[ni][0], acc[AH][BH][mi][ni], 0, 0, 0);                    \
    acc[AH][BH][mi][ni] = __builtin_amdgcn_mfma_f32_16x16x32_bf16(              \
        AF[mi][1], BF[ni][1], acc[AH][BH][mi][ni], 0, 0, 0);                    \
  }                                                                             \
  __builtin_amdgcn_s_setprio(0);

#define ITER8(T, NT)                                                            \
  {                                                                             \
    const int ktO1 = ((T) + 1 < (NT)) ? (T) + 1 : (NT) - 1;                     \
    const int ktE  = ((T) + 2 < (NT)) ? (T) + 2 : (NT) - 1;                     \
    const int ktO  = ((T) + 3 < (NT)) ? (T) + 3 : (NT) - 1;                     \
    STAGE_BH(1, 1, ktO1);                                                       \
    LOAD_AH(0, 0, afA); LOAD_BH(0, 0, bf0);                                     \
    WAIT_LGKM(8); BAR(); WAIT_LGKM(0);                                          \
    MFMA_Q(0, 0, afA, bf0); BAR();                                              \
    STAGE_AH(0, 0, ktE);                                                        \
    LOAD_AH(0, 1, afB);                                                         \
    BAR(); WAIT_LGKM(0);                                                        \
    MFMA_Q(1, 0, afB, bf0); BAR();                                              \
    STAGE_BH(0, 0, ktE);                                                        \
    LOAD_BH(0, 1, bf1);                                                         \
    BAR(); WAIT_LGKM(0);                                                        \
    MFMA_Q(1, 1, afB, bf1); BAR();                                              \
    STAGE_AH(0, 1, ktE);                                                        \
    BAR();                                                                      \
    MFMA_Q(0, 1, afA, bf1);                                                     \
    WAIT_VM(6); BAR();                                                          \
    STAGE_BH(0, 1, ktE);                                                        \
    LOAD_AH(1, 0, afA); LOAD_BH(1, 0, bf0);                                     \
    WAIT_LGKM(8); BAR(); WAIT_LGKM(0);                                          \
    MFMA_Q(0, 0, afA, bf0); BAR();                                              \
    STAGE_AH(1, 0, ktO);                                                        \
    LOAD_AH(1, 1, afB);                                                         \
    BAR(); WAIT_LGKM(0);                                                        \
    MFMA_Q(1, 0, afB, bf0); BAR();                                              \
    STAGE_BH(1, 0, ktO);                                                        \
    LOAD_BH(1, 1, bf1);                                                         \
    BAR(); WAIT_LGKM(0);                                                        \
    MFMA_Q(1, 1, afB, bf1); BAR();                                              \
    STAGE_AH(1, 1, ktO);                                                        \
    BAR();                                                                      \
    MFMA_Q(0, 1, afA, bf1);                                                     \
    WAIT_VM(6); BAR();                                                          \
  }

#define KLOOP8(NT)                                                              \
  {                                                                             \
    const int k1 = 1 < (NT) ? 1 : 0;                                            \
    STAGE_AH(0, 0, 0); STAGE_BH(0, 0, 0); STAGE_AH(0, 1, 0); STAGE_BH(0, 1, 0); \
    STAGE_AH(1, 0, k1); STAGE_BH(1, 0, k1); STAGE_AH(1, 1, k1);                 \
    WAIT_VM(6); BAR();                                                          \
  }                                                                             \
  for (int t = 0; t < (NT); t += 2) ITER8(t, NT)

// ---------------- GEMM1: Hb = gelu(gather(Xb) @ W1t^T + b1) ----------------
__global__ __launch_bounds__(512, 2) void gemm1_kernel(
    const bf16_t* __restrict__ Xb, const bf16_t* __restrict__ W1t,
    const float* __restrict__ b1, const int* __restrict__ ptok,
    const int* __restrict__ meta, bf16_t* __restrict__ Hb) {
  __shared__ __align__(16) char lds[131072];
  GEMM_PRE();
  // banded 2D XCD mapping: each XCD owns a 17-mt strip, walks it in 4 nt-bands.
  // Concurrent 32 blocks/XCD = 8 mt x 4 nt -> B working set 2MB (L2-resident,
  // reused 17x per band); B HBM traffic = compulsory.
  int b = blockIdx.x;                       // 2176 blocks
  int xcd = b & 7, w = b >> 3;              // w in [0,272)
  int band = w / 68, r0i = w % 68;
  const int mt = xcd * 17 + (r0i >> 2);
  const int nt = band * 4 + (r0i & 3);
  const int row0 = mt * 256;
  const int* seg = meta + 16;
  int e = 0;
#pragma unroll
  for (int k = 1; k < NE; ++k) if (row0 >= seg[k]) e = k;
  if (row0 - seg[e] >= meta[e]) return;

  const bf16_t* aSrc[2][2];
  const bf16_t* bSrc[2][2];
#pragma unroll
  for (int h = 0; h < 2; ++h)
#pragma unroll
    for (int j = 0; j < 2; ++j) {
      int idx = j * 512 + tid;
      int rl = idx >> 3, c = idx & 7;
      int cs = c ^ (rl & 7);
      int tok = ptok[row0 + h * 128 + rl];
      if (tok < 0) tok = 0;
      aSrc[h][j] = Xb + (size_t)tok * DIM + cs * 8;
      int brow = nt * 256 + h * 128 + rl;
      bSrc[h][j] = W1t + (size_t)e * HID * DIM + (size_t)brow * DIM + cs * 8;
    }

  f32x4 acc[2][2][4][2] = {};
  bf16x8 afA[4][2], afB[4][2], bf0[2][2], bf1[2][2];
  KLOOP8(DIM / BK);

#pragma unroll
  for (int BH_ = 0; BH_ < 2; ++BH_)
#pragma unroll
  for (int ni = 0; ni < 2; ++ni) {
    int col = nt * 256 + BH_ * 128 + wn * 32 + ni * 16 + l16;
    float bv = b1[e * HID + col];
#pragma unroll
    for (int AH_ = 0; AH_ < 2; ++AH_)
#pragma unroll
    for (int mi = 0; mi < 4; ++mi) {
      int r = row0 + AH_ * 128 + wm * 64 + mi * 16 + qr * 4;
#pragma unroll
      for (int j = 0; j < 4; ++j) {
        float v = acc[AH_][BH_][mi][ni][j] + bv;
        float g2 = 0.5f * v * (1.0f + erff(v * 0.70710678118654752f));
        Hb[(size_t)(r + j) * HID + col] = (bf16_t)g2;
      }
    }
  }
}

// ---------------- GEMM2: out[tok] += w * (Hb @ W2t^T + b2) ----------------
__global__ __launch_bounds__(512, 2) void gemm2_kernel(
    const bf16_t* __restrict__ Hb, const bf16_t* __restrict__ W2t,
    const float* __restrict__ b2, const int* __restrict__ ptok,
    const float* __restrict__ pw, const int* __restrict__ meta,
    float* __restrict__ out) {
  __shared__ __align__(16) char lds[131072];
  GEMM_PRE();
  int b = blockIdx.x;                       // 544 blocks
  int g = (b & 7) * 68 + (b >> 3);
  const int mt = g >> 2, nt = g & 3;
  const int row0 = mt * 256;
  const int* seg = meta + 16;
  int e = 0;
#pragma unroll
  for (int k = 1; k < NE; ++k) if (row0 >= seg[k]) e = k;
  if (row0 - seg[e] >= meta[e]) return;

  const bf16_t* aSrc[2][2];
  const bf16_t* bSrc[2][2];
#pragma unroll
  for (int h = 0; h < 2; ++h)
#pragma unroll
    for (int j = 0; j < 2; ++j) {
      int idx = j * 512 + tid;
      int rl = idx >> 3, c = idx & 7;
      int cs = c ^ (rl & 7);
      aSrc[h][j] = Hb + (size_t)(row0 + h * 128 + rl) * HID + cs * 8;
      int brow = nt * 256 + h * 128 + rl;
      bSrc[h][j] = W2t + (size_t)e * DIM * HID + (size_t)brow * HID + cs * 8;
    }

  f32x4 acc[2][2][4][2] = {};
  bf16x8 afA[4][2], afB[4][2], bf0[2][2], bf1[2][2];
  KLOOP8(HID / BK);

  float bv2[2][2];
#pragma unroll
  for (int BH_ = 0; BH_ < 2; ++BH_)
#pragma unroll
  for (int ni = 0; ni < 2; ++ni)
    bv2[BH_][ni] = b2[e * DIM + nt * 256 + BH_ * 128 + wn * 32 + ni * 16 + l16];

#pragma unroll
  for (int AH_ = 0; AH_ < 2; ++AH_)
#pragma unroll
  for (int mi = 0; mi < 4; ++mi) {
    int r = row0 + AH_ * 128 + wm * 64 + mi * 16 + qr * 4;
    int tk[4]; float wv[4];
#pragma unroll
    for (int j = 0; j < 4; ++j) { tk[j] = ptok[r + j]; wv[j] = pw[r + j]; }
#pragma unroll
    for (int BH_ = 0; BH_ < 2; ++BH_)
#pragma unroll
    for (int ni = 0; ni < 2; ++ni) {
      int col = nt * 256 + BH_ * 128 + wn * 32 + ni * 16 + l16;
#pragma unroll
      for (int j = 0; j < 4; ++j) {
        if (tk[j] >= 0)
          atomicAdd(out + (size_t)tk[j] * DIM + col,
                    wv[j] * (acc[AH_][BH_][mi][ni][j] + bv2[BH_][ni]));
      }
    }
  }
}

extern "C" void kernel_launch(void* const* d_in, const int* in_sizes, int n_in,
                              void* d_out, int out_size, void* d_ws, size_t ws_size,
                              hipStream_t stream) {
  const float* x    = (const float*)d_in[0];
  const float* rw   = (const float*)d_in[1];
  const float* w1   = (const float*)d_in[2];
  const float* b1   = (const float*)d_in[3];
  const float* w2   = (const float*)d_in[4];
  const float* b2   = (const float*)d_in[5];
  const float* bias = (const float*)d_in[6];
  float* out    = (float*)d_out;
  float* logits = out + (size_t)T_TOK * DIM;
  char* ws = (char*)d_ws;

  // big layout: separate W1t/W2t (no overlay) -> 5 launches
  const size_t B_XB  = 0;                    // bf16 [T][D]       33,554,432
  const size_t B_W1T = 33554432;             // bf16 [E][H][D]    67,108,864
  const size_t B_W2T = 100663296;            // bf16 [E][D][H]    67,108,864
  const size_t B_HB  = 167772160;            // bf16 [NSLOT][H]  285,212,672
  const size_t B_PT  = 452984832;            // int  [NSLOT]
  const size_t B_PW  = 453124096;            // f32  [NSLOT]
  const size_t B_TE  = 453263360;            // int  [T*2]
  const size_t B_TW  = 453394432;            // f32  [T*2]
  const size_t B_MT  = 453525504;            // int  [32]
  const size_t NEED_BIG = B_MT + 128;

  // fallback layout (r12, proven): W1t/W2t overlay -> 6 launches
  const size_t F_XB = 0;
  const size_t F_WT = 33554432;
  const size_t F_HB = 100663296;
  const size_t F_PT = 385875968;
  const size_t F_PW = 386015232;
  const size_t F_TE = 386154496;
  const size_t F_TW = 386285568;
  const size_t F_MT = 386416640;
  const size_t NEED_FB = F_MT + 128;

  if (ws_size >= NEED_BIG) {
    bf16_t* Xb  = (bf16_t*)(ws + B_XB);
    bf16_t* W1t = (bf16_t*)(ws + B_W1T);
    bf16_t* W2t = (bf16_t*)(ws + B_W2T);
    bf16_t* Hb  = (bf16_t*)(ws + B_HB);
    int*    ptok= (int*)  (ws + B_PT);
    float*  pwv = (float*)(ws + B_PW);
    int*    te  = (int*)  (ws + B_TE);
    float*  tw  = (float*)(ws + B_TW);
    int*    meta= (int*)  (ws + B_MT);

    router_kernel<<<T_TOK / 4, 256, 0, stream>>>(x, rw, logits, meta, te, tw,
                                                 Xb, ptok, out, bias);
    scatter_kernel<<<T_TOK / 256, 256, 0, stream>>>(te, tw, meta, ptok, pwv);
    transpose_both_kernel<<<4096, 256, 0, stream>>>(w1, w2, W1t, W2t);
    gemm1_kernel<<<2176, 512, 0, stream>>>(Xb, W1t, b1, ptok, meta, Hb);
    gemm2_kernel<<<544, 512, 0, stream>>>(Hb, W2t, b2, ptok, pwv, meta, out);
  } else {
    if (ws_size < NEED_FB) return;
    bf16_t* Xb  = (bf16_t*)(ws + F_XB);
    bf16_t* Wt  = (bf16_t*)(ws + F_WT);
    bf16_t* Hb  = (bf16_t*)(ws + F_HB);
    int*    ptok= (int*)  (ws + F_PT);
    float*  pwv = (float*)(ws + F_PW);
    int*    te  = (int*)  (ws + F_TE);
    float*  tw  = (float*)(ws + F_TW);
    int*    meta= (int*)  (ws + F_MT);

    router_kernel<<<T_TOK / 4, 256, 0, stream>>>(x, rw, logits, meta, te, tw,
                                                 Xb, ptok, out, bias);
    scatter_kernel<<<T_TOK / 256, 256, 0, stream>>>(te, tw, meta, ptok, pwv);
    transpose_cvt_kernel<<<dim3(HID / 256, DIM / 64, NE), 256, 0, stream>>>(w1, Wt, DIM, HID);
    gemm1_kernel<<<2176, 512, 0, stream>>>(Xb, Wt, b1, ptok, meta, Hb);
    transpose_cvt_kernel<<<dim3(DIM / 256, HID / 64, NE), 256, 0, stream>>>(w2, Wt, HID, DIM);
    gemm2_kernel<<<544, 512, 0, stream>>>(Hb, Wt, b2, ptok, pwv, meta, out);
  }
}